// Round 6
// baseline (696.600 us; speedup 1.0000x reference)
//
#include <hip/hip_runtime.h>
#include <math.h>

typedef unsigned short u16;
typedef unsigned int u32;
typedef __attribute__((ext_vector_type(4))) unsigned short u16x4;
typedef __attribute__((ext_vector_type(8))) short bf16x8;
typedef __attribute__((ext_vector_type(4))) float f32x4;

#define B_ 4
#define S_ 2048
#define D_ 1024
#define H_ 16
#define NT (B_*S_)
#define DFF 4096

static __device__ __forceinline__ float bf2f(u16 u) {
    return __uint_as_float(((u32)u) << 16);
}
static __device__ __forceinline__ u16 f2bf(float f) {
    u32 u = __float_as_uint(f);
    u32 r = (u + 0x7fffu + ((u >> 16) & 1u)) >> 16;
    return (u16)r;
}
// async 16B/lane global->LDS (LDS dest = wave-uniform base + lane*16)
static __device__ __forceinline__ void gload_lds16(const void* g, void* l) {
    __builtin_amdgcn_global_load_lds(
        (const __attribute__((address_space(1))) void*)g,
        (__attribute__((address_space(3))) void*)l, 16, 0, 0);
}
// tanh-form GELU via hw exp2: gelu(x) = x*e/(e+1), e = 2^(c*(x+0.044715x^3)),
// c = 2*0.7978845608/ln2. Max abs err ~3e-4 (vs exact-erf GELU) — negligible
// next to bf16 storage rounding. Replaces ~25-inst erff with ~8 inst.
static __device__ __forceinline__ float gelu_fast(float x) {
    float x2 = x * x;
    float u = x * fmaf(0.044715f, x2, 1.0f);
    float e = exp2f(2.3022079f * u);
    float r = __builtin_amdgcn_rcpf(e + 1.0f);
    return x - x * r;       // == x*e/(e+1); e=inf -> x, e=0 -> 0 (no NaN)
}

// ------------------------------------------------- transpose fp32 -> bf16
__global__ void transpose_f2b4(const float* __restrict__ s0, const float* __restrict__ s1,
                               const float* __restrict__ s2, const float* __restrict__ s3,
                               u16* __restrict__ d0, u16* __restrict__ d1,
                               u16* __restrict__ d2, u16* __restrict__ d3,
                               int R, int C) {
    const float* in = s0; u16* out = d0;
    if (blockIdx.z == 1) { in = s1; out = d1; }
    else if (blockIdx.z == 2) { in = s2; out = d2; }
    else if (blockIdx.z == 3) { in = s3; out = d3; }
    __shared__ float t[32][33];
    int c0 = blockIdx.x * 32, r0 = blockIdx.y * 32;
    int x = threadIdx.x, y = threadIdx.y;
    #pragma unroll
    for (int i = 0; i < 4; i++)
        t[y + i*8][x] = in[(long)(r0 + y + i*8) * C + c0 + x];
    __syncthreads();
    #pragma unroll
    for (int i = 0; i < 4; i++)
        out[(long)(c0 + y + i*8) * R + r0 + x] = f2bf(t[x][y + i*8]);
}

__global__ void transpose_f2b(const float* __restrict__ in, u16* __restrict__ out,
                              int R, int C) {
    __shared__ float t[32][33];
    int c0 = blockIdx.x * 32, r0 = blockIdx.y * 32;
    int x = threadIdx.x, y = threadIdx.y;
    #pragma unroll
    for (int i = 0; i < 4; i++)
        t[y + i*8][x] = in[(long)(r0 + y + i*8) * C + c0 + x];
    __syncthreads();
    #pragma unroll
    for (int i = 0; i < 4; i++)
        out[(long)(c0 + y + i*8) * R + r0 + x] = f2bf(t[x][y + i*8]);
}

// V bf16 [B*S][D] -> Vt bf16 [B*H][64][S]. grid (S/32, 2, B*H), block (32,8)
__global__ void transpose_v(const u16* __restrict__ V, u16* __restrict__ Vt) {
    __shared__ u16 t[32][33];
    int z = blockIdx.z; int b = z >> 4, h = z & 15;
    int s0 = blockIdx.x * 32, d0 = blockIdx.y * 32;
    int x = threadIdx.x, y = threadIdx.y;
    const u16* in = V + ((long)b * S_ + s0) * D_ + h * 64 + d0;
    #pragma unroll
    for (int i = 0; i < 4; i++)
        t[y + i*8][x] = in[(long)(y + i*8) * D_ + x];
    __syncthreads();
    u16* out = Vt + ((long)z * 64 + d0) * S_ + s0;
    #pragma unroll
    for (int i = 0; i < 4; i++)
        out[(long)(y + i*8) * S_ + x] = t[x][y + i*8];
}

// ------------------------------------------------- layernorm (fp32 in, bf16 out)
__global__ __launch_bounds__(256) void ln_kernel(
    const float* __restrict__ X, const float* __restrict__ alpha,
    const float* __restrict__ beta, u16* __restrict__ Y) {
    int row = blockIdx.x, tid = threadIdx.x;
    float4 xv = ((const float4*)(X + (long)row * D_))[tid];
    float v[4] = {xv.x, xv.y, xv.z, xv.w};
    float s = 0.f, ss = 0.f;
    #pragma unroll
    for (int i = 0; i < 4; i++) { s += v[i]; ss += v[i]*v[i]; }
    #pragma unroll
    for (int off = 32; off >= 1; off >>= 1) {
        s += __shfl_xor(s, off);
        ss += __shfl_xor(ss, off);
    }
    __shared__ float red[8];
    __shared__ float stats[2];
    int w = tid >> 6;
    if ((tid & 63) == 0) { red[w] = s; red[4 + w] = ss; }
    __syncthreads();
    if (tid == 0) {
        float S = red[0] + red[1] + red[2] + red[3];
        float SS = red[4] + red[5] + red[6] + red[7];
        float mean = S * (1.f / D_);
        float var = SS * (1.f / D_) - mean * mean;
        stats[0] = mean; stats[1] = rsqrtf(var + 1e-5f);
    }
    __syncthreads();
    float mean = stats[0], rstd = stats[1];
    float4 av = ((const float4*)alpha)[tid];
    float4 bv = ((const float4*)beta)[tid];
    u16x4 o;
    o[0] = f2bf((v[0] - mean) * rstd * av.x + bv.x);
    o[1] = f2bf((v[1] - mean) * rstd * av.y + bv.y);
    o[2] = f2bf((v[2] - mean) * rstd * av.z + bv.z);
    o[3] = f2bf((v[3] - mean) * rstd * av.w + bv.w);
    *(u16x4*)(Y + (long)row * D_ + tid * 4) = o;
}

// ------------------------------------------------- GEMM 128^2 (bf16 A, bf16 B^T)
// BASELINE m97 recipe, untouched. Used for Wo (mode 1) and W2 (mode 3):
// N=1024 -> only 128 blocks at a 256^2 tile (half the CUs idle), and W2's
// K=4096 amortizes this structure's per-step stall well.
#define BM 128
#define BN 128
#define BK 64

__global__ __launch_bounds__(256, 3) void gemm_bt(
    const u16* __restrict__ A,
    const u16* __restrict__ Bt0, const u16* __restrict__ Bt1, const u16* __restrict__ Bt2,
    void* __restrict__ C0, void* __restrict__ C1, void* __restrict__ C2,
    int M, int N, int K, int mode,
    const float* __restrict__ bias, const float* __restrict__ resid) {
    const u16* Bt = Bt0; void* C = C0;
    if (blockIdx.z == 1) { Bt = Bt1; C = C1; }
    else if (blockIdx.z == 2) { Bt = Bt2; C = C2; }

    __shared__ __align__(16) u16 Asm[BM * BK];
    __shared__ __align__(16) u16 Bsm[BN * BK];

    int tid = threadIdx.x;
    int lane = tid & 63, wave = tid >> 6;
    int l15 = lane & 15, quad = lane >> 4;
    int wm = wave & 1, wn = wave >> 1;
    long tm0 = (long)blockIdx.y * BM, tn0 = (long)blockIdx.x * BN;

    int srow = lane >> 3;
    int scol = (lane & 7) * 8;

    f32x4 acc[4][4] = {};

    for (int k0 = 0; k0 < K; k0 += BK) {
        __syncthreads();
        #pragma unroll
        for (int c = 0; c < 4; c++) {
            int chunk = wave * 4 + c;
            int row = chunk * 8 + srow;
            gload_lds16(&A[(tm0 + row) * (long)K + k0 + scol], &Asm[chunk * 512]);
            gload_lds16(&Bt[(tn0 + row) * (long)K + k0 + scol], &Bsm[chunk * 512]);
        }
        __syncthreads();
        #pragma unroll
        for (int ks = 0; ks < 2; ks++) {
            bf16x8 af[4], bfm[4];
            #pragma unroll
            for (int mt = 0; mt < 4; mt++)
                af[mt] = *(const bf16x8*)&Asm[(wm*64 + mt*16 + l15) * BK + ks*32 + quad*8];
            #pragma unroll
            for (int nt = 0; nt < 4; nt++)
                bfm[nt] = *(const bf16x8*)&Bsm[(wn*64 + nt*16 + l15) * BK + ks*32 + quad*8];
            #pragma unroll
            for (int mt = 0; mt < 4; mt++)
                #pragma unroll
                for (int nt = 0; nt < 4; nt++)
                    acc[mt][nt] = __builtin_amdgcn_mfma_f32_16x16x32_bf16(
                        af[mt], bfm[nt], acc[mt][nt], 0, 0, 0);
        }
    }

    #pragma unroll
    for (int mt = 0; mt < 4; mt++) {
        #pragma unroll
        for (int nt = 0; nt < 4; nt++) {
            #pragma unroll
            for (int i = 0; i < 4; i++) {
                long r = tm0 + wm*64 + mt*16 + quad*4 + i;
                long cn = tn0 + wn*64 + nt*16 + l15;
                long idx = r * N + cn;
                float val = acc[mt][nt][i];
                if (mode == 0) {
                    ((u16*)C)[idx] = f2bf(val);
                } else if (mode == 1) {
                    ((float*)C)[idx] = val + resid[idx];
                } else if (mode == 2) {
                    val += bias[cn];
                    val = 0.5f * val * (1.0f + erff(val * 0.70710678118654752f));
                    ((u16*)C)[idx] = f2bf(val);
                } else {
                    ((float*)C)[idx] = val + bias[cn] + resid[idx];
                }
            }
        }
    }
}

// ------------------------------------------------- GEMM 256^2 (QKV + W1)
// R14: same m97 skeleton, 256x256 tile, 512 threads = 8 waves (2M x 4N),
// LDS still 64 KB (single-buffered). 2x arithmetic intensity per staged
// byte AND per barrier-drain (64 MFMA/wave/step vs 32) — attacks the
// short-K (K=1024, 16 steps) stall-domination that holds W1 at 458 TF /
// MfmaUtil 19%. Proven 792 TF at this structure (m105-m112 tile table).
// 1 block/CU (acc[8][4]=128 VGPR => 2 waves/SIMD cap). Mode 2 uses
// gelu_fast: 128 erff/thread (~3200 VALU inst) was comparable to the
// whole K-loop MFMA issue time.
#define BM2 256
#define BN2 256
#define BK2 64

__global__ __launch_bounds__(512, 2) void gemm256(
    const u16* __restrict__ A,
    const u16* __restrict__ Bt0, const u16* __restrict__ Bt1, const u16* __restrict__ Bt2,
    void* __restrict__ C0, void* __restrict__ C1, void* __restrict__ C2,
    int M, int N, int K, int mode, const float* __restrict__ bias) {
    const u16* Bt = Bt0; void* C = C0;
    if (blockIdx.z == 1) { Bt = Bt1; C = C1; }
    else if (blockIdx.z == 2) { Bt = Bt2; C = C2; }

    __shared__ __align__(16) u16 Asm[BM2 * BK2];   // 32 KB
    __shared__ __align__(16) u16 Bsm[BN2 * BK2];   // 32 KB

    int tid = threadIdx.x;
    int lane = tid & 63, wave = tid >> 6;          // wave 0..7
    int l15 = lane & 15, quad = lane >> 4;
    int wm = wave & 1, wn = wave >> 1;             // M-half, N-quarter
    long tm0 = (long)blockIdx.y * BM2, tn0 = (long)blockIdx.x * BN2;

    int srow = lane >> 3;
    int scol = (lane & 7) * 8;

    f32x4 acc[8][4] = {};

    for (int k0 = 0; k0 < K; k0 += BK2) {
        __syncthreads();
        #pragma unroll
        for (int c = 0; c < 4; c++) {
            int chunk = wave * 4 + c;              // 0..31 (8 rows each)
            int row = chunk * 8 + srow;            // 0..255
            gload_lds16(&A[(tm0 + row) * (long)K + k0 + scol], &Asm[chunk * 512]);
            gload_lds16(&Bt[(tn0 + row) * (long)K + k0 + scol], &Bsm[chunk * 512]);
        }
        __syncthreads();
        #pragma unroll
        for (int ks = 0; ks < 2; ks++) {
            bf16x8 af[8], bfm[4];
            #pragma unroll
            for (int mt = 0; mt < 8; mt++)
                af[mt] = *(const bf16x8*)&Asm[(wm*128 + mt*16 + l15) * BK2 + ks*32 + quad*8];
            #pragma unroll
            for (int nt = 0; nt < 4; nt++)
                bfm[nt] = *(const bf16x8*)&Bsm[(wn*64 + nt*16 + l15) * BK2 + ks*32 + quad*8];
            #pragma unroll
            for (int mt = 0; mt < 8; mt++)
                #pragma unroll
                for (int nt = 0; nt < 4; nt++)
                    acc[mt][nt] = __builtin_amdgcn_mfma_f32_16x16x32_bf16(
                        af[mt], bfm[nt], acc[mt][nt], 0, 0, 0);
        }
    }

    #pragma unroll
    for (int mt = 0; mt < 8; mt++) {
        #pragma unroll
        for (int nt = 0; nt < 4; nt++) {
            #pragma unroll
            for (int i = 0; i < 4; i++) {
                long r = tm0 + wm*128 + mt*16 + quad*4 + i;
                long cn = tn0 + wn*64 + nt*16 + l15;
                long idx = r * N + cn;
                float val = acc[mt][nt][i];
                if (mode == 0) {
                    ((u16*)C)[idx] = f2bf(val);
                } else {   // mode 2: bias + GELU -> bf16
                    val += bias[cn];
                    ((u16*)C)[idx] = f2bf(gelu_fast(val));
                }
            }
        }
    }
}

// ------------------------------------------------- attention
// R13 kernel (KEEP): one q-tile per WAVE, grid (64,16) = 1024 blocks,
// LDS = Psm only (18.4 KB) -> 4 blocks/CU. Dropped attn from 186 us to
// <149 us (out of top-5). Wave->tile map per block y: w0->y, w1->63-y,
// w2->31-y, w3->32+y (bijective, balanced). Zero barriers.
#define LDP 72   // P row stride in u16

__global__ __launch_bounds__(256, 2) void attn_kernel(
    const u16* __restrict__ Q, const u16* __restrict__ Kg, const u16* __restrict__ Vt,
    const int* __restrict__ mask, u16* __restrict__ O) {
    __shared__ __align__(16) u16 Psm[4][32 * LDP];
    int tid = threadIdx.x;
    int lane = tid & 63, wave = tid >> 6;
    int l15 = lane & 15, quad = lane >> 4;
    int bh = blockIdx.x; int b = bh >> 4, h = bh & 15;
    int y = blockIdx.y;                // 0..15
    long tokBase = (long)b * S_;
    const float SCL = 0.125f * 1.4426950408889634f;  // exp2 domain
    const float MMAX = 20.0f;                        // fixed softmax shift

    const bf16x8 ones = {16256,16256,16256,16256,16256,16256,16256,16256}; // bf16 1.0
    u16* Pw = Psm[wave];
    const int* mb = mask + b * S_;

    int t;                             // q-tile 0..63, one per wave
    if (wave == 0)      t = y;
    else if (wave == 1) t = 63 - y;
    else if (wave == 2) t = 31 - y;
    else                t = 32 + y;
    int q0 = t * 32;

    bf16x8 aq[2][2];
    #pragma unroll
    for (int mt = 0; mt < 2; mt++) {
        const u16* qptr = Q + (tokBase + q0 + mt*16 + l15) * D_ + h * 64;
        aq[mt][0] = *(const bf16x8*)(qptr + quad * 8);
        aq[mt][1] = *(const bf16x8*)(qptr + 32 + quad * 8);
    }

    f32x4 o[2][4] = {};
    f32x4 lacc[2] = {};
    int ktiles = t / 2 + 1;

    for (int kt = 0; kt < ktiles; kt++) {
        int k0 = kt * 64;
        bf16x8 kb[4][2], vb[4][2];
        #pragma unroll
        for (int nt = 0; nt < 4; nt++) {
            const u16* kp = Kg + (tokBase + k0 + nt*16 + l15) * D_ + h * 64;
            kb[nt][0] = *(const bf16x8*)(kp + quad * 8);
            kb[nt][1] = *(const bf16x8*)(kp + 32 + quad * 8);
        }
        #pragma unroll
        for (int d = 0; d < 4; d++) {
            const u16* vp = Vt + ((long)bh * 64 + d*16 + l15) * S_ + k0;
            vb[d][0] = *(const bf16x8*)(vp + quad * 8);
            vb[d][1] = *(const bf16x8*)(vp + 32 + quad * 8);
        }

        f32x4 s[2][4] = {};
        #pragma unroll
        for (int nt = 0; nt < 4; nt++) {
            s[0][nt] = __builtin_amdgcn_mfma_f32_16x16x32_bf16(aq[0][0], kb[nt][0], s[0][nt], 0,0,0);
            s[0][nt] = __builtin_amdgcn_mfma_f32_16x16x32_bf16(aq[0][1], kb[nt][1], s[0][nt], 0,0,0);
            s[1][nt] = __builtin_amdgcn_mfma_f32_16x16x32_bf16(aq[1][0], kb[nt][0], s[1][nt], 0,0,0);
            s[1][nt] = __builtin_amdgcn_mfma_f32_16x16x32_bf16(aq[1][1], kb[nt][1], s[1][nt], 0,0,0);
        }

        int mk = 0;
        #pragma unroll
        for (int nt = 0; nt < 4; nt++)
            if (mb[k0 + nt*16 + l15] != 0) mk |= (1 << nt);

        #pragma unroll
        for (int mt = 0; mt < 2; mt++) {
            #pragma unroll
            for (int i = 0; i < 4; i++) {
                int qq = q0 + mt*16 + quad*4 + i;
                #pragma unroll
                for (int nt = 0; nt < 4; nt++) {
                    int kc = k0 + nt*16 + l15;
                    float p = exp2f(fmaf(s[mt][nt][i], SCL, -MMAX));
                    p = (kc <= qq && ((mk >> nt) & 1)) ? p : 0.f;
                    Pw[(mt*16 + quad*4 + i) * LDP + nt*16 + l15] = f2bf(p);
                }
            }
        }
        // same-wave P write -> read ordering (P is wave-private)
        asm volatile("s_waitcnt lgkmcnt(0)" ::: "memory");

        #pragma unroll
        for (int hv = 0; hv < 2; hv++) {
            bf16x8 ap0 = *(const bf16x8*)&Pw[l15 * LDP + hv*32 + quad*8];
            bf16x8 ap1 = *(const bf16x8*)&Pw[(16 + l15) * LDP + hv*32 + quad*8];
            #pragma unroll
            for (int d = 0; d < 4; d++) {
                o[0][d] = __builtin_amdgcn_mfma_f32_16x16x32_bf16(ap0, vb[d][hv], o[0][d], 0,0,0);
                o[1][d] = __builtin_amdgcn_mfma_f32_16x16x32_bf16(ap1, vb[d][hv], o[1][d], 0,0,0);
            }
            lacc[0] = __builtin_amdgcn_mfma_f32_16x16x32_bf16(ap0, ones, lacc[0], 0,0,0);
            lacc[1] = __builtin_amdgcn_mfma_f32_16x16x32_bf16(ap1, ones, lacc[1], 0,0,0);
        }
    }

    #pragma unroll
    for (int mt = 0; mt < 2; mt++) {
        #pragma unroll
        for (int i = 0; i < 4; i++) {
            float inv = 1.f / lacc[mt][i];
            long r = tokBase + q0 + mt*16 + quad*4 + i;
            #pragma unroll
            for (int d = 0; d < 4; d++)
                O[r * D_ + h*64 + d*16 + l15] = f2bf(o[mt][d][i] * inv);
        }
    }
}

// ------------------------------------------------- launch
extern "C" void kernel_launch(void* const* d_in, const int* in_sizes, int n_in,
                              void* d_out, int out_size, void* d_ws, size_t ws_size,
                              hipStream_t stream) {
    const float* x    = (const float*)d_in[0];
    const int*   am   = (const int*)d_in[1];
    const float* ln1a = (const float*)d_in[2];
    const float* ln1b = (const float*)d_in[3];
    const float* ln2a = (const float*)d_in[4];
    const float* ln2b = (const float*)d_in[5];
    const float* wq   = (const float*)d_in[6];
    const float* wk   = (const float*)d_in[7];
    const float* wv   = (const float*)d_in[8];
    const float* wo   = (const float*)d_in[9];
    const float* w1   = (const float*)d_in[10];
    const float* b1   = (const float*)d_in[11];
    const float* w2   = (const float*)d_in[12];
    const float* b2   = (const float*)d_in[13];
    float* out = (float*)d_out;

    // Workspace: 72 MB, liveness-overlapped 16MB slots.
    char* ws = (char*)d_ws;
    const size_t MB16 = (size_t)16 * 1024 * 1024;
    u16* y1      = (u16*)(ws + 0 * MB16);
    u16* q       = (u16*)(ws + 1 * MB16);
    u16* k       = (u16*)(ws + 2 * MB16);
    u16* v       = (u16*)(ws + 3 * MB16);
    u16* wqt     = (u16*)(ws + 4 * MB16 + 0 * (size_t)D_ * D_ * 2);
    u16* wkt     = (u16*)(ws + 4 * MB16 + 1 * (size_t)D_ * D_ * 2);
    u16* wvt     = (u16*)(ws + 4 * MB16 + 2 * (size_t)D_ * D_ * 2);
    u16* wot     = (u16*)(ws + 4 * MB16 + 3 * (size_t)D_ * D_ * 2);
    u16* y2      = y1;
    u16* w1t     = q;
    u16* w2t     = q + (size_t)D_ * DFF;
    u16* h_full  = k;
    u16* ctx     = v;
    u16*   vt  = (u16*)d_out;                // d_out scratch; dead after attn
    float* x1f = out;

    dim3 tb(32, 8);
    transpose_f2b4<<<dim3(D_/32, D_/32, 4), tb, 0, stream>>>(
        wq, wk, wv, wo, wqt, wkt, wvt, wot, D_, D_);

    ln_kernel<<<NT, 256, 0, stream>>>(x, ln1a, ln1b, y1);

    gemm256<<<dim3(D_/BN2, NT/BM2, 3), 512, 0, stream>>>(
        y1, wqt, wkt, wvt, q, k, v, NT, D_, D_, 0, nullptr);

    transpose_v<<<dim3(S_/32, 2, B_*H_), tb, 0, stream>>>(v, vt);

    attn_kernel<<<dim3(B_*H_, 16), 256, 0, stream>>>(q, k, vt, am, ctx);

    gemm_bt<<<dim3(D_/BN, NT/BM, 1), 256, 0, stream>>>(
        ctx, wot, wot, wot, x1f, x1f, x1f, NT, D_, D_, 1, nullptr, x);

    transpose_f2b<<<dim3(DFF/32, D_/32), tb, 0, stream>>>(w1, w1t, D_, DFF);
    transpose_f2b<<<dim3(D_/32, DFF/32), tb, 0, stream>>>(w2, w2t, DFF, D_);

    ln_kernel<<<NT, 256, 0, stream>>>(x1f, ln2a, ln2b, y2);

    gemm256<<<dim3(DFF/BN2, NT/BM2, 1), 512, 0, stream>>>(
        y2, w1t, w1t, w1t, h_full, h_full, h_full, NT, DFF, D_, 2, b1);
    gemm_bt<<<dim3(D_/BN, NT/BM, 1), 256, 0, stream>>>(
        h_full, w2t, w2t, w2t, out, out, out, NT, D_, DFF, 3, b2, x1f);
}

// Round 7
// 676.346 us; speedup vs baseline: 1.0299x; 1.0299x over previous
//
#include <hip/hip_runtime.h>
#include <math.h>

typedef unsigned short u16;
typedef unsigned int u32;
typedef __attribute__((ext_vector_type(4))) unsigned short u16x4;
typedef __attribute__((ext_vector_type(8))) short bf16x8;
typedef __attribute__((ext_vector_type(4))) float f32x4;

#define B_ 4
#define S_ 2048
#define D_ 1024
#define H_ 16
#define NT (B_*S_)
#define DFF 4096

static __device__ __forceinline__ float bf2f(u16 u) {
    return __uint_as_float(((u32)u) << 16);
}
static __device__ __forceinline__ u16 f2bf(float f) {
    u32 u = __float_as_uint(f);
    u32 r = (u + 0x7fffu + ((u >> 16) & 1u)) >> 16;
    return (u16)r;
}
// async 16B/lane global->LDS (LDS dest = wave-uniform base + lane*16)
static __device__ __forceinline__ void gload_lds16(const void* g, void* l) {
    __builtin_amdgcn_global_load_lds(
        (const __attribute__((address_space(1))) void*)g,
        (__attribute__((address_space(3))) void*)l, 16, 0, 0);
}
// tanh-form GELU via hw exp2 (validated R14: passed absmax 0.0625).
static __device__ __forceinline__ float gelu_fast(float x) {
    float x2 = x * x;
    float u = x * fmaf(0.044715f, x2, 1.0f);
    float e = exp2f(2.3022079f * u);
    float r = __builtin_amdgcn_rcpf(e + 1.0f);
    return x - x * r;
}

// raw barrier (no implicit vmcnt(0) drain, unlike __syncthreads) with
// compiler memory fences so C++ LDS reads can't be hoisted across it.
#define MBAR() do { asm volatile("" ::: "memory"); \
                    __builtin_amdgcn_s_barrier(); \
                    asm volatile("" ::: "memory"); } while (0)

// ------------------------------------------------- transpose fp32 -> bf16
__global__ void transpose_f2b4(const float* __restrict__ s0, const float* __restrict__ s1,
                               const float* __restrict__ s2, const float* __restrict__ s3,
                               u16* __restrict__ d0, u16* __restrict__ d1,
                               u16* __restrict__ d2, u16* __restrict__ d3,
                               int R, int C) {
    const float* in = s0; u16* out = d0;
    if (blockIdx.z == 1) { in = s1; out = d1; }
    else if (blockIdx.z == 2) { in = s2; out = d2; }
    else if (blockIdx.z == 3) { in = s3; out = d3; }
    __shared__ float t[32][33];
    int c0 = blockIdx.x * 32, r0 = blockIdx.y * 32;
    int x = threadIdx.x, y = threadIdx.y;
    #pragma unroll
    for (int i = 0; i < 4; i++)
        t[y + i*8][x] = in[(long)(r0 + y + i*8) * C + c0 + x];
    __syncthreads();
    #pragma unroll
    for (int i = 0; i < 4; i++)
        out[(long)(c0 + y + i*8) * R + r0 + x] = f2bf(t[x][y + i*8]);
}

__global__ void transpose_f2b(const float* __restrict__ in, u16* __restrict__ out,
                              int R, int C) {
    __shared__ float t[32][33];
    int c0 = blockIdx.x * 32, r0 = blockIdx.y * 32;
    int x = threadIdx.x, y = threadIdx.y;
    #pragma unroll
    for (int i = 0; i < 4; i++)
        t[y + i*8][x] = in[(long)(r0 + y + i*8) * C + c0 + x];
    __syncthreads();
    #pragma unroll
    for (int i = 0; i < 4; i++)
        out[(long)(c0 + y + i*8) * R + r0 + x] = f2bf(t[x][y + i*8]);
}

// V bf16 [B*S][D] -> Vt bf16 [B*H][64][S]. grid (S/32, 2, B*H), block (32,8)
__global__ void transpose_v(const u16* __restrict__ V, u16* __restrict__ Vt) {
    __shared__ u16 t[32][33];
    int z = blockIdx.z; int b = z >> 4, h = z & 15;
    int s0 = blockIdx.x * 32, d0 = blockIdx.y * 32;
    int x = threadIdx.x, y = threadIdx.y;
    const u16* in = V + ((long)b * S_ + s0) * D_ + h * 64 + d0;
    #pragma unroll
    for (int i = 0; i < 4; i++)
        t[y + i*8][x] = in[(long)(y + i*8) * D_ + x];
    __syncthreads();
    u16* out = Vt + ((long)z * 64 + d0) * S_ + s0;
    #pragma unroll
    for (int i = 0; i < 4; i++)
        out[(long)(y + i*8) * S_ + x] = t[x][y + i*8];
}

// ------------------------------------------------- layernorm (fp32 in, bf16 out)
__global__ __launch_bounds__(256) void ln_kernel(
    const float* __restrict__ X, const float* __restrict__ alpha,
    const float* __restrict__ beta, u16* __restrict__ Y) {
    int row = blockIdx.x, tid = threadIdx.x;
    float4 xv = ((const float4*)(X + (long)row * D_))[tid];
    float v[4] = {xv.x, xv.y, xv.z, xv.w};
    float s = 0.f, ss = 0.f;
    #pragma unroll
    for (int i = 0; i < 4; i++) { s += v[i]; ss += v[i]*v[i]; }
    #pragma unroll
    for (int off = 32; off >= 1; off >>= 1) {
        s += __shfl_xor(s, off);
        ss += __shfl_xor(ss, off);
    }
    __shared__ float red[8];
    __shared__ float stats[2];
    int w = tid >> 6;
    if ((tid & 63) == 0) { red[w] = s; red[4 + w] = ss; }
    __syncthreads();
    if (tid == 0) {
        float S = red[0] + red[1] + red[2] + red[3];
        float SS = red[4] + red[5] + red[6] + red[7];
        float mean = S * (1.f / D_);
        float var = SS * (1.f / D_) - mean * mean;
        stats[0] = mean; stats[1] = rsqrtf(var + 1e-5f);
    }
    __syncthreads();
    float mean = stats[0], rstd = stats[1];
    float4 av = ((const float4*)alpha)[tid];
    float4 bv = ((const float4*)beta)[tid];
    u16x4 o;
    o[0] = f2bf((v[0] - mean) * rstd * av.x + bv.x);
    o[1] = f2bf((v[1] - mean) * rstd * av.y + bv.y);
    o[2] = f2bf((v[2] - mean) * rstd * av.z + bv.z);
    o[3] = f2bf((v[3] - mean) * rstd * av.w + bv.w);
    *(u16x4*)(Y + (long)row * D_ + tid * 4) = o;
}

// ------------------------------------------------- GEMM 128^2 (Wo, W2)
// BASELINE m97 recipe, untouched. N=1024 shapes (128 blocks at 256^2 tile
// would idle half the CUs) stay here.
#define BM 128
#define BN 128
#define BK 64

__global__ __launch_bounds__(256, 3) void gemm_bt(
    const u16* __restrict__ A,
    const u16* __restrict__ Bt0, const u16* __restrict__ Bt1, const u16* __restrict__ Bt2,
    void* __restrict__ C0, void* __restrict__ C1, void* __restrict__ C2,
    int M, int N, int K, int mode,
    const float* __restrict__ bias, const float* __restrict__ resid) {
    const u16* Bt = Bt0; void* C = C0;
    if (blockIdx.z == 1) { Bt = Bt1; C = C1; }
    else if (blockIdx.z == 2) { Bt = Bt2; C = C2; }

    __shared__ __align__(16) u16 Asm[BM * BK];
    __shared__ __align__(16) u16 Bsm[BN * BK];

    int tid = threadIdx.x;
    int lane = tid & 63, wave = tid >> 6;
    int l15 = lane & 15, quad = lane >> 4;
    int wm = wave & 1, wn = wave >> 1;
    long tm0 = (long)blockIdx.y * BM, tn0 = (long)blockIdx.x * BN;

    int srow = lane >> 3;
    int scol = (lane & 7) * 8;

    f32x4 acc[4][4] = {};

    for (int k0 = 0; k0 < K; k0 += BK) {
        __syncthreads();
        #pragma unroll
        for (int c = 0; c < 4; c++) {
            int chunk = wave * 4 + c;
            int row = chunk * 8 + srow;
            gload_lds16(&A[(tm0 + row) * (long)K + k0 + scol], &Asm[chunk * 512]);
            gload_lds16(&Bt[(tn0 + row) * (long)K + k0 + scol], &Bsm[chunk * 512]);
        }
        __syncthreads();
        #pragma unroll
        for (int ks = 0; ks < 2; ks++) {
            bf16x8 af[4], bfm[4];
            #pragma unroll
            for (int mt = 0; mt < 4; mt++)
                af[mt] = *(const bf16x8*)&Asm[(wm*64 + mt*16 + l15) * BK + ks*32 + quad*8];
            #pragma unroll
            for (int nt = 0; nt < 4; nt++)
                bfm[nt] = *(const bf16x8*)&Bsm[(wn*64 + nt*16 + l15) * BK + ks*32 + quad*8];
            #pragma unroll
            for (int mt = 0; mt < 4; mt++)
                #pragma unroll
                for (int nt = 0; nt < 4; nt++)
                    acc[mt][nt] = __builtin_amdgcn_mfma_f32_16x16x32_bf16(
                        af[mt], bfm[nt], acc[mt][nt], 0, 0, 0);
        }
    }

    #pragma unroll
    for (int mt = 0; mt < 4; mt++) {
        #pragma unroll
        for (int nt = 0; nt < 4; nt++) {
            #pragma unroll
            for (int i = 0; i < 4; i++) {
                long r = tm0 + wm*64 + mt*16 + quad*4 + i;
                long cn = tn0 + wn*64 + nt*16 + l15;
                long idx = r * N + cn;
                float val = acc[mt][nt][i];
                if (mode == 0) {
                    ((u16*)C)[idx] = f2bf(val);
                } else if (mode == 1) {
                    ((float*)C)[idx] = val + resid[idx];
                } else if (mode == 2) {
                    val += bias[cn];
                    ((u16*)C)[idx] = f2bf(gelu_fast(val));
                } else {
                    ((float*)C)[idx] = val + bias[cn] + resid[idx];
                }
            }
        }
    }
}

// ------------------------------------------------- GEMM 256^2 8-phase (QKV fused, W1)
// R15: T3+T4 port (counted vmcnt, raw barriers). 2-phase structures are
// pinned at MfmaUtil ~18% here (R14 null proved it); the 8-phase schedule
// is the measured lever (m196->m198 +28-41%; counted-vs-drain0 +38-73%).
// Geometry: 256x256 tile, BK=64, 8 waves (2M x 4N), per-wave C = 128x64.
// LDS 128 KB: 2 bufs x (A[256][64] + B[256][64]). Phase plan per K-tile t
// (cur=t&1): quadrants Q1(mlo,nlo) Q2(mlo,nhi) Q3(mhi,nhi) Q4(mhi,nlo);
// B-lo frags HELD in regs (read ph1, reused ph4) so B region is fully
// consumed by ph2-end; A by ph3-end. Staging rotation (1 half-tile = 128
// rows x 64 = 2 gload_lds/thread per phase):
//   ph1: A-lo(t+1)->buf^1   [that region free since t-1 ph3]
//   ph2: A-hi(t+1)->buf^1
//   ph3: B-lo(t+2)->buf     [free at this tile's ph2-end barrier]
//   ph4: B-hi(t+2)->buf
// One s_waitcnt vmcnt(4) per K-tile (after ph4 MFMA): forces A(t+1)+B(t+1)
// landed, leaves B(t+2)'s 4 loads in flight. Tail tiles drain to 0.
// setprio(1) around MFMA clusters (T5 pays only in this regime).
#define BM2 256
#define BN2 256
#define BK2 64

__global__ __launch_bounds__(512, 2) void gemm8p(
    const u16* __restrict__ A, const u16* __restrict__ Bt,
    u16* __restrict__ C0, u16* __restrict__ C1, u16* __restrict__ C2,
    int N, int K, int mode, const float* __restrict__ bias) {
    __shared__ __align__(16) u16 lds[2 * 32768];   // 128 KB

    int tid = threadIdx.x;
    int lane = tid & 63, wave = tid >> 6;          // wave 0..7
    int l15 = lane & 15, quad = lane >> 4;
    int wm = wave & 1, wn = wave >> 1;             // M half, N quarter
    long tm0 = (long)blockIdx.y * BM2, tn0 = (long)blockIdx.x * BN2;
    int srow = lane >> 3;
    int scol = (lane & 7) * 8;
    int steps = K >> 6;

    // stage one half-tile (half: 0=A-lo,1=A-hi,2=B-lo,3=B-hi) of K-tile kt
    // into buffer buf. Per thread: 2 gload_lds (wave covers 2 chunks of 8 rows).
    auto STAGE = [&](int kt, int half, int buf) {
        long kk = (long)kt * BK2;
        #pragma unroll
        for (int c = 0; c < 2; c++) {
            int chunk = wave * 2 + c;                       // 0..15
            int rloc = (half & 1) * 128 + chunk * 8 + srow; // row in tile
            const u16* g = (half < 2)
                ? &A [(tm0 + rloc) * (long)K + kk + scol]
                : &Bt[(tn0 + rloc) * (long)K + kk + scol];
            u16* l = &lds[buf * 32768 + (half >= 2 ? 16384 : 0)
                          + (half & 1) * 8192 + chunk * 512];
            gload_lds16(g, l);
        }
    };

    f32x4 acc[8][4] = {};
    bf16x8 af[4][2], bl[2][2], bh[2][2];

    // ---- prologue: tile0 (all 4 halves) -> buf0, B(1) -> buf1
    STAGE(0, 0, 0); STAGE(0, 1, 0); STAGE(0, 2, 0); STAGE(0, 3, 0);
    if (steps > 1) { STAGE(1, 2, 1); STAGE(1, 3, 1); }
    if (steps > 1) asm volatile("s_waitcnt vmcnt(4)" ::: "memory");
    else           asm volatile("s_waitcnt vmcnt(0)" ::: "memory");
    MBAR();

    for (int t = 0; t < steps; ++t) {
        int cur = t & 1;
        const u16* Ab = &lds[cur * 32768];
        const u16* Bb = &lds[cur * 32768 + 16384];
        bool pf1 = (t + 1 < steps), pf2 = (t + 2 < steps);

        // ---- ph1: read A-mlo + B-nlo; stage A-lo(t+1); MFMA Q(mlo,nlo)
        #pragma unroll
        for (int mt = 0; mt < 4; mt++) {
            const u16* p = &Ab[(wm*128 + mt*16 + l15) * BK2];
            af[mt][0] = *(const bf16x8*)(p + quad*8);
            af[mt][1] = *(const bf16x8*)(p + 32 + quad*8);
        }
        #pragma unroll
        for (int nt = 0; nt < 2; nt++) {
            const u16* p = &Bb[(wn*64 + nt*16 + l15) * BK2];
            bl[nt][0] = *(const bf16x8*)(p + quad*8);
            bl[nt][1] = *(const bf16x8*)(p + 32 + quad*8);
        }
        if (pf1) STAGE(t + 1, 0, cur ^ 1);
        MBAR();
        __builtin_amdgcn_s_setprio(1);
        #pragma unroll
        for (int mt = 0; mt < 4; mt++)
            #pragma unroll
            for (int nt = 0; nt < 2; nt++) {
                acc[mt][nt] = __builtin_amdgcn_mfma_f32_16x16x32_bf16(af[mt][0], bl[nt][0], acc[mt][nt], 0,0,0);
                acc[mt][nt] = __builtin_amdgcn_mfma_f32_16x16x32_bf16(af[mt][1], bl[nt][1], acc[mt][nt], 0,0,0);
            }
        __builtin_amdgcn_s_setprio(0);
        MBAR();

        // ---- ph2: read B-nhi; stage A-hi(t+1); MFMA Q(mlo,nhi)
        #pragma unroll
        for (int nt = 0; nt < 2; nt++) {
            const u16* p = &Bb[(wn*64 + (2+nt)*16 + l15) * BK2];
            bh[nt][0] = *(const bf16x8*)(p + quad*8);
            bh[nt][1] = *(const bf16x8*)(p + 32 + quad*8);
        }
        if (pf1) STAGE(t + 1, 1, cur ^ 1);
        MBAR();
        __builtin_amdgcn_s_setprio(1);
        #pragma unroll
        for (int mt = 0; mt < 4; mt++)
            #pragma unroll
            for (int nt = 0; nt < 2; nt++) {
                acc[mt][2+nt] = __builtin_amdgcn_mfma_f32_16x16x32_bf16(af[mt][0], bh[nt][0], acc[mt][2+nt], 0,0,0);
                acc[mt][2+nt] = __builtin_amdgcn_mfma_f32_16x16x32_bf16(af[mt][1], bh[nt][1], acc[mt][2+nt], 0,0,0);
            }
        __builtin_amdgcn_s_setprio(0);
        MBAR();

        // ---- ph3: read A-mhi (reuse af regs); stage B-lo(t+2); MFMA Q(mhi,nhi)
        #pragma unroll
        for (int mt = 0; mt < 4; mt++) {
            const u16* p = &Ab[(wm*128 + 64 + mt*16 + l15) * BK2];
            af[mt][0] = *(const bf16x8*)(p + quad*8);
            af[mt][1] = *(const bf16x8*)(p + 32 + quad*8);
        }
        if (pf2) STAGE(t + 2, 2, cur);
        MBAR();
        __builtin_amdgcn_s_setprio(1);
        #pragma unroll
        for (int mt = 0; mt < 4; mt++)
            #pragma unroll
            for (int nt = 0; nt < 2; nt++) {
                acc[4+mt][2+nt] = __builtin_amdgcn_mfma_f32_16x16x32_bf16(af[mt][0], bh[nt][0], acc[4+mt][2+nt], 0,0,0);
                acc[4+mt][2+nt] = __builtin_amdgcn_mfma_f32_16x16x32_bf16(af[mt][1], bh[nt][1], acc[4+mt][2+nt], 0,0,0);
            }
        __builtin_amdgcn_s_setprio(0);
        MBAR();

        // ---- ph4: stage B-hi(t+2); MFMA Q(mhi,nlo) (bl held from ph1); tile-end vmcnt
        if (pf2) STAGE(t + 2, 3, cur);
        MBAR();
        __builtin_amdgcn_s_setprio(1);
        #pragma unroll
        for (int mt = 0; mt < 4; mt++)
            #pragma unroll
            for (int nt = 0; nt < 2; nt++) {
                acc[4+mt][nt] = __builtin_amdgcn_mfma_f32_16x16x32_bf16(af[mt][0], bl[nt][0], acc[4+mt][nt], 0,0,0);
                acc[4+mt][nt] = __builtin_amdgcn_mfma_f32_16x16x32_bf16(af[mt][1], bl[nt][1], acc[4+mt][nt], 0,0,0);
            }
        __builtin_amdgcn_s_setprio(0);
        if (pf2) asm volatile("s_waitcnt vmcnt(4)" ::: "memory");
        else     asm volatile("s_waitcnt vmcnt(0)" ::: "memory");
        MBAR();
    }

    // ---- epilogue
    #pragma unroll
    for (int mt = 0; mt < 8; mt++) {
        #pragma unroll
        for (int nt = 0; nt < 4; nt++) {
            #pragma unroll
            for (int i = 0; i < 4; i++) {
                long r = tm0 + wm*128 + mt*16 + quad*4 + i;
                int cn = (int)tn0 + wn*64 + nt*16 + l15;
                float val = acc[mt][nt][i];
                if (mode == 0) {           // fused QKV: route to q/k/v slabs
                    int mi = cn >> 10;
                    int col = cn & 1023;
                    u16* base = (mi == 0) ? C0 : (mi == 1 ? C1 : C2);
                    base[r * 1024 + col] = f2bf(val);
                } else {                   // mode 2: bias + GELU -> bf16
                    val += bias[cn];
                    C0[r * (long)N + cn] = f2bf(gelu_fast(val));
                }
            }
        }
    }
}

// ------------------------------------------------- attention
// R13 kernel (KEEP): one q-tile per WAVE, grid (64,16) = 1024 blocks,
// LDS = Psm only (18.4 KB) -> 4 blocks/CU. attn 186 -> <149 us.
#define LDP 72   // P row stride in u16

__global__ __launch_bounds__(256, 2) void attn_kernel(
    const u16* __restrict__ Q, const u16* __restrict__ Kg, const u16* __restrict__ Vt,
    const int* __restrict__ mask, u16* __restrict__ O) {
    __shared__ __align__(16) u16 Psm[4][32 * LDP];
    int tid = threadIdx.x;
    int lane = tid & 63, wave = tid >> 6;
    int l15 = lane & 15, quad = lane >> 4;
    int bh = blockIdx.x; int b = bh >> 4, h = bh & 15;
    int y = blockIdx.y;                // 0..15
    long tokBase = (long)b * S_;
    const float SCL = 0.125f * 1.4426950408889634f;  // exp2 domain
    const float MMAX = 20.0f;                        // fixed softmax shift

    const bf16x8 ones = {16256,16256,16256,16256,16256,16256,16256,16256}; // bf16 1.0
    u16* Pw = Psm[wave];
    const int* mb = mask + b * S_;

    int t;                             // q-tile 0..63, one per wave
    if (wave == 0)      t = y;
    else if (wave == 1) t = 63 - y;
    else if (wave == 2) t = 31 - y;
    else                t = 32 + y;
    int q0 = t * 32;

    bf16x8 aq[2][2];
    #pragma unroll
    for (int mt = 0; mt < 2; mt++) {
        const u16* qptr = Q + (tokBase + q0 + mt*16 + l15) * D_ + h * 64;
        aq[mt][0] = *(const bf16x8*)(qptr + quad * 8);
        aq[mt][1] = *(const bf16x8*)(qptr + 32 + quad * 8);
    }

    f32x4 o[2][4] = {};
    f32x4 lacc[2] = {};
    int ktiles = t / 2 + 1;

    for (int kt = 0; kt < ktiles; kt++) {
        int k0 = kt * 64;
        bf16x8 kb[4][2], vb[4][2];
        #pragma unroll
        for (int nt = 0; nt < 4; nt++) {
            const u16* kp = Kg + (tokBase + k0 + nt*16 + l15) * D_ + h * 64;
            kb[nt][0] = *(const bf16x8*)(kp + quad * 8);
            kb[nt][1] = *(const bf16x8*)(kp + 32 + quad * 8);
        }
        #pragma unroll
        for (int d = 0; d < 4; d++) {
            const u16* vp = Vt + ((long)bh * 64 + d*16 + l15) * S_ + k0;
            vb[d][0] = *(const bf16x8*)(vp + quad * 8);
            vb[d][1] = *(const bf16x8*)(vp + 32 + quad * 8);
        }

        f32x4 s[2][4] = {};
        #pragma unroll
        for (int nt = 0; nt < 4; nt++) {
            s[0][nt] = __builtin_amdgcn_mfma_f32_16x16x32_bf16(aq[0][0], kb[nt][0], s[0][nt], 0,0,0);
            s[0][nt] = __builtin_amdgcn_mfma_f32_16x16x32_bf16(aq[0][1], kb[nt][1], s[0][nt], 0,0,0);
            s[1][nt] = __builtin_amdgcn_mfma_f32_16x16x32_bf16(aq[1][0], kb[nt][0], s[1][nt], 0,0,0);
            s[1][nt] = __builtin_amdgcn_mfma_f32_16x16x32_bf16(aq[1][1], kb[nt][1], s[1][nt], 0,0,0);
        }

        int mk = 0;
        #pragma unroll
        for (int nt = 0; nt < 4; nt++)
            if (mb[k0 + nt*16 + l15] != 0) mk |= (1 << nt);

        #pragma unroll
        for (int mt = 0; mt < 2; mt++) {
            #pragma unroll
            for (int i = 0; i < 4; i++) {
                int qq = q0 + mt*16 + quad*4 + i;
                #pragma unroll
                for (int nt = 0; nt < 4; nt++) {
                    int kc = k0 + nt*16 + l15;
                    float p = exp2f(fmaf(s[mt][nt][i], SCL, -MMAX));
                    p = (kc <= qq && ((mk >> nt) & 1)) ? p : 0.f;
                    Pw[(mt*16 + quad*4 + i) * LDP + nt*16 + l15] = f2bf(p);
                }
            }
        }
        // same-wave P write -> read ordering (P is wave-private)
        asm volatile("s_waitcnt lgkmcnt(0)" ::: "memory");

        #pragma unroll
        for (int hv = 0; hv < 2; hv++) {
            bf16x8 ap0 = *(const bf16x8*)&Pw[l15 * LDP + hv*32 + quad*8];
            bf16x8 ap1 = *(const bf16x8*)&Pw[(16 + l15) * LDP + hv*32 + quad*8];
            #pragma unroll
            for (int d = 0; d < 4; d++) {
                o[0][d] = __builtin_amdgcn_mfma_f32_16x16x32_bf16(ap0, vb[d][hv], o[0][d], 0,0,0);
                o[1][d] = __builtin_amdgcn_mfma_f32_16x16x32_bf16(ap1, vb[d][hv], o[1][d], 0,0,0);
            }
            lacc[0] = __builtin_amdgcn_mfma_f32_16x16x32_bf16(ap0, ones, lacc[0], 0,0,0);
            lacc[1] = __builtin_amdgcn_mfma_f32_16x16x32_bf16(ap1, ones, lacc[1], 0,0,0);
        }
    }

    #pragma unroll
    for (int mt = 0; mt < 2; mt++) {
        #pragma unroll
        for (int i = 0; i < 4; i++) {
            float inv = 1.f / lacc[mt][i];
            long r = tokBase + q0 + mt*16 + quad*4 + i;
            #pragma unroll
            for (int d = 0; d < 4; d++)
                O[r * D_ + h*64 + d*16 + l15] = f2bf(o[mt][d][i] * inv);
        }
    }
}

// ------------------------------------------------- launch
extern "C" void kernel_launch(void* const* d_in, const int* in_sizes, int n_in,
                              void* d_out, int out_size, void* d_ws, size_t ws_size,
                              hipStream_t stream) {
    const float* x    = (const float*)d_in[0];
    const int*   am   = (const int*)d_in[1];
    const float* ln1a = (const float*)d_in[2];
    const float* ln1b = (const float*)d_in[3];
    const float* ln2a = (const float*)d_in[4];
    const float* ln2b = (const float*)d_in[5];
    const float* wq   = (const float*)d_in[6];
    const float* wk   = (const float*)d_in[7];
    const float* wv   = (const float*)d_in[8];
    const float* wo   = (const float*)d_in[9];
    const float* w1   = (const float*)d_in[10];
    const float* b1   = (const float*)d_in[11];
    const float* w2   = (const float*)d_in[12];
    const float* b2   = (const float*)d_in[13];
    float* out = (float*)d_out;

    // Workspace: 72 MB, liveness-overlapped 16MB slots.
    char* ws = (char*)d_ws;
    const size_t MB16 = (size_t)16 * 1024 * 1024;
    u16* y1      = (u16*)(ws + 0 * MB16);
    u16* q       = (u16*)(ws + 1 * MB16);
    u16* k       = (u16*)(ws + 2 * MB16);
    u16* v       = (u16*)(ws + 3 * MB16);
    u16* wqt     = (u16*)(ws + 4 * MB16 + 0 * (size_t)D_ * D_ * 2);
    u16* wkt     = (u16*)(ws + 4 * MB16 + 1 * (size_t)D_ * D_ * 2);
    u16* wvt     = (u16*)(ws + 4 * MB16 + 2 * (size_t)D_ * D_ * 2);
    u16* wot     = (u16*)(ws + 4 * MB16 + 3 * (size_t)D_ * D_ * 2);
    u16* y2      = y1;
    u16* w1t     = q;
    u16* w2t     = q + (size_t)D_ * DFF;
    u16* h_full  = k;
    u16* ctx     = v;
    u16*   vt  = (u16*)d_out;                // d_out scratch; dead after attn
    float* x1f = out;

    dim3 tb(32, 8);
    transpose_f2b4<<<dim3(D_/32, D_/32, 4), tb, 0, stream>>>(
        wq, wk, wv, wo, wqt, wkt, wvt, wot, D_, D_);

    ln_kernel<<<NT, 256, 0, stream>>>(x, ln1a, ln1b, y1);

    // fused QKV: wqt/wkt/wvt are contiguous -> one [3072][1024] B matrix
    gemm8p<<<dim3(3*D_/BN2, NT/BM2), 512, 0, stream>>>(
        y1, wqt, q, k, v, 3*D_, D_, 0, nullptr);

    transpose_v<<<dim3(S_/32, 2, B_*H_), tb, 0, stream>>>(v, vt);

    attn_kernel<<<dim3(B_*H_, 16), 256, 0, stream>>>(q, k, vt, am, ctx);

    gemm_bt<<<dim3(D_/BN, NT/BM, 1), 256, 0, stream>>>(
        ctx, wot, wot, wot, x1f, x1f, x1f, NT, D_, D_, 1, nullptr, x);

    transpose_f2b<<<dim3(DFF/32, D_/32), tb, 0, stream>>>(w1, w1t, D_, DFF);
    transpose_f2b<<<dim3(D_/32, DFF/32), tb, 0, stream>>>(w2, w2t, DFF, D_);

    ln_kernel<<<NT, 256, 0, stream>>>(x1f, ln2a, ln2b, y2);

    gemm8p<<<dim3(DFF/BN2, NT/BM2), 512, 0, stream>>>(
        y2, w1t, h_full, h_full, h_full, DFF, D_, 2, b1);
    gemm_bt<<<dim3(D_/BN, NT/BM, 1), 256, 0, stream>>>(
        h_full, w2t, w2t, w2t, out, out, out, NT, D_, DFF, 3, b2, x1f);
}

// Round 8
// 633.268 us; speedup vs baseline: 1.1000x; 1.0680x over previous
//
#include <hip/hip_runtime.h>
#include <math.h>

typedef unsigned short u16;
typedef unsigned int u32;
typedef __attribute__((ext_vector_type(4))) unsigned short u16x4;
typedef __attribute__((ext_vector_type(8))) short bf16x8;
typedef __attribute__((ext_vector_type(4))) float f32x4;

#define B_ 4
#define S_ 2048
#define D_ 1024
#define H_ 16
#define NT (B_*S_)
#define DFF 4096

static __device__ __forceinline__ float bf2f(u16 u) {
    return __uint_as_float(((u32)u) << 16);
}
static __device__ __forceinline__ u16 f2bf(float f) {
    u32 u = __float_as_uint(f);
    u32 r = (u + 0x7fffu + ((u >> 16) & 1u)) >> 16;
    return (u16)r;
}
// async 16B/lane global->LDS (LDS dest = wave-uniform base + lane*16)
static __device__ __forceinline__ void gload_lds16(const void* g, void* l) {
    __builtin_amdgcn_global_load_lds(
        (const __attribute__((address_space(1))) void*)g,
        (__attribute__((address_space(3))) void*)l, 16, 0, 0);
}
// tanh-form GELU via hw exp2 (validated R14: passed absmax 0.0625).
static __device__ __forceinline__ float gelu_fast(float x) {
    float x2 = x * x;
    float u = x * fmaf(0.044715f, x2, 1.0f);
    float e = exp2f(2.3022079f * u);
    float r = __builtin_amdgcn_rcpf(e + 1.0f);
    return x - x * r;
}

// raw barrier (no implicit vmcnt(0) drain, unlike __syncthreads) with
// compiler memory fences so C++ LDS reads can't be hoisted across it.
#define MBAR() do { asm volatile("" ::: "memory"); \
                    __builtin_amdgcn_s_barrier(); \
                    asm volatile("" ::: "memory"); } while (0)

// ------------------------------------------------- transpose fp32 -> bf16
__global__ void transpose_f2b4(const float* __restrict__ s0, const float* __restrict__ s1,
                               const float* __restrict__ s2, const float* __restrict__ s3,
                               u16* __restrict__ d0, u16* __restrict__ d1,
                               u16* __restrict__ d2, u16* __restrict__ d3,
                               int R, int C) {
    const float* in = s0; u16* out = d0;
    if (blockIdx.z == 1) { in = s1; out = d1; }
    else if (blockIdx.z == 2) { in = s2; out = d2; }
    else if (blockIdx.z == 3) { in = s3; out = d3; }
    __shared__ float t[32][33];
    int c0 = blockIdx.x * 32, r0 = blockIdx.y * 32;
    int x = threadIdx.x, y = threadIdx.y;
    #pragma unroll
    for (int i = 0; i < 4; i++)
        t[y + i*8][x] = in[(long)(r0 + y + i*8) * C + c0 + x];
    __syncthreads();
    #pragma unroll
    for (int i = 0; i < 4; i++)
        out[(long)(c0 + y + i*8) * R + r0 + x] = f2bf(t[x][y + i*8]);
}

__global__ void transpose_f2b(const float* __restrict__ in, u16* __restrict__ out,
                              int R, int C) {
    __shared__ float t[32][33];
    int c0 = blockIdx.x * 32, r0 = blockIdx.y * 32;
    int x = threadIdx.x, y = threadIdx.y;
    #pragma unroll
    for (int i = 0; i < 4; i++)
        t[y + i*8][x] = in[(long)(r0 + y + i*8) * C + c0 + x];
    __syncthreads();
    #pragma unroll
    for (int i = 0; i < 4; i++)
        out[(long)(c0 + y + i*8) * R + r0 + x] = f2bf(t[x][y + i*8]);
}

// V bf16 [B*S][D] -> Vt bf16 [B*H][64][S]. grid (S/32, 2, B*H), block (32,8)
__global__ void transpose_v(const u16* __restrict__ V, u16* __restrict__ Vt) {
    __shared__ u16 t[32][33];
    int z = blockIdx.z; int b = z >> 4, h = z & 15;
    int s0 = blockIdx.x * 32, d0 = blockIdx.y * 32;
    int x = threadIdx.x, y = threadIdx.y;
    const u16* in = V + ((long)b * S_ + s0) * D_ + h * 64 + d0;
    #pragma unroll
    for (int i = 0; i < 4; i++)
        t[y + i*8][x] = in[(long)(y + i*8) * D_ + x];
    __syncthreads();
    u16* out = Vt + ((long)z * 64 + d0) * S_ + s0;
    #pragma unroll
    for (int i = 0; i < 4; i++)
        out[(long)(y + i*8) * S_ + x] = t[x][y + i*8];
}

// ------------------------------------------------- layernorm (fp32 in, bf16 out)
__global__ __launch_bounds__(256) void ln_kernel(
    const float* __restrict__ X, const float* __restrict__ alpha,
    const float* __restrict__ beta, u16* __restrict__ Y) {
    int row = blockIdx.x, tid = threadIdx.x;
    float4 xv = ((const float4*)(X + (long)row * D_))[tid];
    float v[4] = {xv.x, xv.y, xv.z, xv.w};
    float s = 0.f, ss = 0.f;
    #pragma unroll
    for (int i = 0; i < 4; i++) { s += v[i]; ss += v[i]*v[i]; }
    #pragma unroll
    for (int off = 32; off >= 1; off >>= 1) {
        s += __shfl_xor(s, off);
        ss += __shfl_xor(ss, off);
    }
    __shared__ float red[8];
    __shared__ float stats[2];
    int w = tid >> 6;
    if ((tid & 63) == 0) { red[w] = s; red[4 + w] = ss; }
    __syncthreads();
    if (tid == 0) {
        float S = red[0] + red[1] + red[2] + red[3];
        float SS = red[4] + red[5] + red[6] + red[7];
        float mean = S * (1.f / D_);
        float var = SS * (1.f / D_) - mean * mean;
        stats[0] = mean; stats[1] = rsqrtf(var + 1e-5f);
    }
    __syncthreads();
    float mean = stats[0], rstd = stats[1];
    float4 av = ((const float4*)alpha)[tid];
    float4 bv = ((const float4*)beta)[tid];
    u16x4 o;
    o[0] = f2bf((v[0] - mean) * rstd * av.x + bv.x);
    o[1] = f2bf((v[1] - mean) * rstd * av.y + bv.y);
    o[2] = f2bf((v[2] - mean) * rstd * av.z + bv.z);
    o[3] = f2bf((v[3] - mean) * rstd * av.w + bv.w);
    *(u16x4*)(Y + (long)row * D_ + tid * 4) = o;
}

// ------------------------------------------------- GEMM 128^2 (Wo, W2)
// BASELINE m97 recipe, untouched. N=1024 shapes stay here.
#define BM 128
#define BN 128
#define BK 64

__global__ __launch_bounds__(256, 3) void gemm_bt(
    const u16* __restrict__ A,
    const u16* __restrict__ Bt0, const u16* __restrict__ Bt1, const u16* __restrict__ Bt2,
    void* __restrict__ C0, void* __restrict__ C1, void* __restrict__ C2,
    int M, int N, int K, int mode,
    const float* __restrict__ bias, const float* __restrict__ resid) {
    const u16* Bt = Bt0; void* C = C0;
    if (blockIdx.z == 1) { Bt = Bt1; C = C1; }
    else if (blockIdx.z == 2) { Bt = Bt2; C = C2; }

    __shared__ __align__(16) u16 Asm[BM * BK];
    __shared__ __align__(16) u16 Bsm[BN * BK];

    int tid = threadIdx.x;
    int lane = tid & 63, wave = tid >> 6;
    int l15 = lane & 15, quad = lane >> 4;
    int wm = wave & 1, wn = wave >> 1;
    long tm0 = (long)blockIdx.y * BM, tn0 = (long)blockIdx.x * BN;

    int srow = lane >> 3;
    int scol = (lane & 7) * 8;

    f32x4 acc[4][4] = {};

    for (int k0 = 0; k0 < K; k0 += BK) {
        __syncthreads();
        #pragma unroll
        for (int c = 0; c < 4; c++) {
            int chunk = wave * 4 + c;
            int row = chunk * 8 + srow;
            gload_lds16(&A[(tm0 + row) * (long)K + k0 + scol], &Asm[chunk * 512]);
            gload_lds16(&Bt[(tn0 + row) * (long)K + k0 + scol], &Bsm[chunk * 512]);
        }
        __syncthreads();
        #pragma unroll
        for (int ks = 0; ks < 2; ks++) {
            bf16x8 af[4], bfm[4];
            #pragma unroll
            for (int mt = 0; mt < 4; mt++)
                af[mt] = *(const bf16x8*)&Asm[(wm*64 + mt*16 + l15) * BK + ks*32 + quad*8];
            #pragma unroll
            for (int nt = 0; nt < 4; nt++)
                bfm[nt] = *(const bf16x8*)&Bsm[(wn*64 + nt*16 + l15) * BK + ks*32 + quad*8];
            #pragma unroll
            for (int mt = 0; mt < 4; mt++)
                #pragma unroll
                for (int nt = 0; nt < 4; nt++)
                    acc[mt][nt] = __builtin_amdgcn_mfma_f32_16x16x32_bf16(
                        af[mt], bfm[nt], acc[mt][nt], 0, 0, 0);
        }
    }

    #pragma unroll
    for (int mt = 0; mt < 4; mt++) {
        #pragma unroll
        for (int nt = 0; nt < 4; nt++) {
            #pragma unroll
            for (int i = 0; i < 4; i++) {
                long r = tm0 + wm*64 + mt*16 + quad*4 + i;
                long cn = tn0 + wn*64 + nt*16 + l15;
                long idx = r * N + cn;
                float val = acc[mt][nt][i];
                if (mode == 0) {
                    ((u16*)C)[idx] = f2bf(val);
                } else if (mode == 1) {
                    ((float*)C)[idx] = val + resid[idx];
                } else if (mode == 2) {
                    val += bias[cn];
                    ((u16*)C)[idx] = f2bf(gelu_fast(val));
                } else {
                    ((float*)C)[idx] = val + bias[cn] + resid[idx];
                }
            }
        }
    }
}

// ------------------------------------------------- GEMM 256^2 8-phase (QKV fused, W1)
// R16: R15's 8-phase schedule + T2 XOR-swizzle. R15 landed the structure
// (passed, ~142 us each) but was null vs 2-phase: [256][64]-bf16 LDS rows
// are 128 B = exactly 32 banks, so every ds_read_b128 column-slice was a
// 16-way conflict. Fix per rule #21 (gload_lds writes linearly): keep LDS
// dest LINEAR, inverse-XOR the GLOBAL source chunk in STAGE, XOR the read
// chunk. Key = row&7 == l15&7 == srow -> per-thread CONSTANT, zero extra
// per-read VALU. Expected (m201): conflicts ~141x down, MfmaUtil -> 45+.
#define BM2 256
#define BN2 256
#define BK2 64

__global__ __launch_bounds__(512, 2) void gemm8p(
    const u16* __restrict__ A, const u16* __restrict__ Bt,
    u16* __restrict__ C0, u16* __restrict__ C1, u16* __restrict__ C2,
    int N, int K, int mode, const float* __restrict__ bias) {
    __shared__ __align__(16) u16 lds[2 * 32768];   // 128 KB

    int tid = threadIdx.x;
    int lane = tid & 63, wave = tid >> 6;          // wave 0..7
    int l15 = lane & 15, quad = lane >> 4;
    int wm = wave & 1, wn = wave >> 1;             // M half, N quarter
    long tm0 = (long)blockIdx.y * BM2, tn0 = (long)blockIdx.x * BN2;
    int srow = lane >> 3;
    // T2 write-side: lane (srow, j) must deposit global chunk j^srow so that
    // LDS slot (row, c') holds global chunk c'^(row&7).
    int scolw = ((lane & 7) ^ srow) * 8;
    // T2 read-side: chunk for (h, quad) at row with row&7 == l15&7.
    int sk = l15 & 7;
    int ca0 = ((quad) ^ sk) * 8;        // h=0 chunk offset (u16)
    int ca1 = ((4 + quad) ^ sk) * 8;    // h=1 chunk offset (u16)
    int steps = K >> 6;

    // stage one half-tile (half: 0=A-lo,1=A-hi,2=B-lo,3=B-hi) of K-tile kt.
    auto STAGE = [&](int kt, int half, int buf) {
        long kk = (long)kt * BK2;
        #pragma unroll
        for (int c = 0; c < 2; c++) {
            int chunk = wave * 2 + c;                       // 0..15
            int rloc = (half & 1) * 128 + chunk * 8 + srow; // row in tile
            const u16* g = (half < 2)
                ? &A [(tm0 + rloc) * (long)K + kk + scolw]
                : &Bt[(tn0 + rloc) * (long)K + kk + scolw];
            u16* l = &lds[buf * 32768 + (half >= 2 ? 16384 : 0)
                          + (half & 1) * 8192 + chunk * 512];
            gload_lds16(g, l);
        }
    };

    f32x4 acc[8][4] = {};
    bf16x8 af[4][2], bl[2][2], bh[2][2];

    // ---- prologue: tile0 (all 4 halves) -> buf0, B(1) -> buf1
    STAGE(0, 0, 0); STAGE(0, 1, 0); STAGE(0, 2, 0); STAGE(0, 3, 0);
    if (steps > 1) { STAGE(1, 2, 1); STAGE(1, 3, 1); }
    if (steps > 1) asm volatile("s_waitcnt vmcnt(4)" ::: "memory");
    else           asm volatile("s_waitcnt vmcnt(0)" ::: "memory");
    MBAR();

    for (int t = 0; t < steps; ++t) {
        int cur = t & 1;
        const u16* Ab = &lds[cur * 32768];
        const u16* Bb = &lds[cur * 32768 + 16384];
        bool pf1 = (t + 1 < steps), pf2 = (t + 2 < steps);

        // ---- ph1: read A-mlo + B-nlo; stage A-lo(t+1); MFMA Q(mlo,nlo)
        #pragma unroll
        for (int mt = 0; mt < 4; mt++) {
            int row = wm*128 + mt*16 + l15;
            af[mt][0] = *(const bf16x8*)&Ab[row * BK2 + ca0];
            af[mt][1] = *(const bf16x8*)&Ab[row * BK2 + ca1];
        }
        #pragma unroll
        for (int nt = 0; nt < 2; nt++) {
            int row = wn*64 + nt*16 + l15;
            bl[nt][0] = *(const bf16x8*)&Bb[row * BK2 + ca0];
            bl[nt][1] = *(const bf16x8*)&Bb[row * BK2 + ca1];
        }
        if (pf1) STAGE(t + 1, 0, cur ^ 1);
        MBAR();
        __builtin_amdgcn_s_setprio(1);
        #pragma unroll
        for (int mt = 0; mt < 4; mt++)
            #pragma unroll
            for (int nt = 0; nt < 2; nt++) {
                acc[mt][nt] = __builtin_amdgcn_mfma_f32_16x16x32_bf16(af[mt][0], bl[nt][0], acc[mt][nt], 0,0,0);
                acc[mt][nt] = __builtin_amdgcn_mfma_f32_16x16x32_bf16(af[mt][1], bl[nt][1], acc[mt][nt], 0,0,0);
            }
        __builtin_amdgcn_s_setprio(0);
        MBAR();

        // ---- ph2: read B-nhi; stage A-hi(t+1); MFMA Q(mlo,nhi)
        #pragma unroll
        for (int nt = 0; nt < 2; nt++) {
            int row = wn*64 + (2+nt)*16 + l15;
            bh[nt][0] = *(const bf16x8*)&Bb[row * BK2 + ca0];
            bh[nt][1] = *(const bf16x8*)&Bb[row * BK2 + ca1];
        }
        if (pf1) STAGE(t + 1, 1, cur ^ 1);
        MBAR();
        __builtin_amdgcn_s_setprio(1);
        #pragma unroll
        for (int mt = 0; mt < 4; mt++)
            #pragma unroll
            for (int nt = 0; nt < 2; nt++) {
                acc[mt][2+nt] = __builtin_amdgcn_mfma_f32_16x16x32_bf16(af[mt][0], bh[nt][0], acc[mt][2+nt], 0,0,0);
                acc[mt][2+nt] = __builtin_amdgcn_mfma_f32_16x16x32_bf16(af[mt][1], bh[nt][1], acc[mt][2+nt], 0,0,0);
            }
        __builtin_amdgcn_s_setprio(0);
        MBAR();

        // ---- ph3: read A-mhi (reuse af regs); stage B-lo(t+2); MFMA Q(mhi,nhi)
        #pragma unroll
        for (int mt = 0; mt < 4; mt++) {
            int row = wm*128 + 64 + mt*16 + l15;
            af[mt][0] = *(const bf16x8*)&Ab[row * BK2 + ca0];
            af[mt][1] = *(const bf16x8*)&Ab[row * BK2 + ca1];
        }
        if (pf2) STAGE(t + 2, 2, cur);
        MBAR();
        __builtin_amdgcn_s_setprio(1);
        #pragma unroll
        for (int mt = 0; mt < 4; mt++)
            #pragma unroll
            for (int nt = 0; nt < 2; nt++) {
                acc[4+mt][2+nt] = __builtin_amdgcn_mfma_f32_16x16x32_bf16(af[mt][0], bh[nt][0], acc[4+mt][2+nt], 0,0,0);
                acc[4+mt][2+nt] = __builtin_amdgcn_mfma_f32_16x16x32_bf16(af[mt][1], bh[nt][1], acc[4+mt][2+nt], 0,0,0);
            }
        __builtin_amdgcn_s_setprio(0);
        MBAR();

        // ---- ph4: stage B-hi(t+2); MFMA Q(mhi,nlo) (bl held from ph1); tile-end vmcnt
        if (pf2) STAGE(t + 2, 3, cur);
        MBAR();
        __builtin_amdgcn_s_setprio(1);
        #pragma unroll
        for (int mt = 0; mt < 4; mt++)
            #pragma unroll
            for (int nt = 0; nt < 2; nt++) {
                acc[4+mt][nt] = __builtin_amdgcn_mfma_f32_16x16x32_bf16(af[mt][0], bl[nt][0], acc[4+mt][nt], 0,0,0);
                acc[4+mt][nt] = __builtin_amdgcn_mfma_f32_16x16x32_bf16(af[mt][1], bl[nt][1], acc[4+mt][nt], 0,0,0);
            }
        __builtin_amdgcn_s_setprio(0);
        if (pf2) asm volatile("s_waitcnt vmcnt(4)" ::: "memory");
        else     asm volatile("s_waitcnt vmcnt(0)" ::: "memory");
        MBAR();
    }

    // ---- epilogue
    #pragma unroll
    for (int mt = 0; mt < 8; mt++) {
        #pragma unroll
        for (int nt = 0; nt < 4; nt++) {
            #pragma unroll
            for (int i = 0; i < 4; i++) {
                long r = tm0 + wm*128 + mt*16 + quad*4 + i;
                int cn = (int)tn0 + wn*64 + nt*16 + l15;
                float val = acc[mt][nt][i];
                if (mode == 0) {           // fused QKV: route to q/k/v slabs
                    int mi = cn >> 10;
                    int col = cn & 1023;
                    u16* base = (mi == 0) ? C0 : (mi == 1 ? C1 : C2);
                    base[r * 1024 + col] = f2bf(val);
                } else {                   // mode 2: bias + GELU -> bf16
                    val += bias[cn];
                    C0[r * (long)N + cn] = f2bf(gelu_fast(val));
                }
            }
        }
    }
}

// ------------------------------------------------- attention
// R16: R13 structure + K-prefetch. The per-tile chain was
// loads->QK->softmax->lgkmcnt->PV; next tile's K loads sat below the fence,
// exposing L2 latency each tile. Now kb(t+1) issues BEFORE softmax(t)
// (global loads count in vmcnt, not lgkmcnt -> the LDS fence doesn't drain
// them), hiding K latency under ~600cyc of softmax VALU. +32 VGPR (~120,
// under the 128 / 4-waves-per-SIMD boundary).
#define LDP 72   // P row stride in u16

__global__ __launch_bounds__(256, 2) void attn_kernel(
    const u16* __restrict__ Q, const u16* __restrict__ Kg, const u16* __restrict__ Vt,
    const int* __restrict__ mask, u16* __restrict__ O) {
    __shared__ __align__(16) u16 Psm[4][32 * LDP];
    int tid = threadIdx.x;
    int lane = tid & 63, wave = tid >> 6;
    int l15 = lane & 15, quad = lane >> 4;
    int bh = blockIdx.x; int b = bh >> 4, h = bh & 15;
    int y = blockIdx.y;                // 0..15
    long tokBase = (long)b * S_;
    const float SCL = 0.125f * 1.4426950408889634f;  // exp2 domain
    const float MMAX = 20.0f;                        // fixed softmax shift

    const bf16x8 ones = {16256,16256,16256,16256,16256,16256,16256,16256}; // bf16 1.0
    u16* Pw = Psm[wave];
    const int* mb = mask + b * S_;

    int t;                             // q-tile 0..63, one per wave
    if (wave == 0)      t = y;
    else if (wave == 1) t = 63 - y;
    else if (wave == 2) t = 31 - y;
    else                t = 32 + y;
    int q0 = t * 32;

    bf16x8 aq[2][2];
    #pragma unroll
    for (int mt = 0; mt < 2; mt++) {
        const u16* qptr = Q + (tokBase + q0 + mt*16 + l15) * D_ + h * 64;
        aq[mt][0] = *(const bf16x8*)(qptr + quad * 8);
        aq[mt][1] = *(const bf16x8*)(qptr + 32 + quad * 8);
    }

    f32x4 o[2][4] = {};
    f32x4 lacc[2] = {};
    int ktiles = t / 2 + 1;

    // prefetch kb for kt=0
    bf16x8 kb[4][2];
    #pragma unroll
    for (int nt = 0; nt < 4; nt++) {
        const u16* kp = Kg + (tokBase + nt*16 + l15) * D_ + h * 64;
        kb[nt][0] = *(const bf16x8*)(kp + quad * 8);
        kb[nt][1] = *(const bf16x8*)(kp + 32 + quad * 8);
    }

    for (int kt = 0; kt < ktiles; kt++) {
        int k0 = kt * 64;
        bf16x8 vb[4][2];
        #pragma unroll
        for (int d = 0; d < 4; d++) {
            const u16* vp = Vt + ((long)bh * 64 + d*16 + l15) * S_ + k0;
            vb[d][0] = *(const bf16x8*)(vp + quad * 8);
            vb[d][1] = *(const bf16x8*)(vp + 32 + quad * 8);
        }

        f32x4 s[2][4] = {};
        #pragma unroll
        for (int nt = 0; nt < 4; nt++) {
            s[0][nt] = __builtin_amdgcn_mfma_f32_16x16x32_bf16(aq[0][0], kb[nt][0], s[0][nt], 0,0,0);
            s[0][nt] = __builtin_amdgcn_mfma_f32_16x16x32_bf16(aq[0][1], kb[nt][1], s[0][nt], 0,0,0);
            s[1][nt] = __builtin_amdgcn_mfma_f32_16x16x32_bf16(aq[1][0], kb[nt][0], s[1][nt], 0,0,0);
            s[1][nt] = __builtin_amdgcn_mfma_f32_16x16x32_bf16(aq[1][1], kb[nt][1], s[1][nt], 0,0,0);
        }

        // prefetch kb(t+1) NOW — latency hides under the softmax below.
        // Wave-uniform clamped address (dead data on last tile, always in-bounds).
        int k1 = (kt + 1 < ktiles) ? k0 + 64 : k0;
        bf16x8 kbn[4][2];
        #pragma unroll
        for (int nt = 0; nt < 4; nt++) {
            const u16* kp = Kg + (tokBase + k1 + nt*16 + l15) * D_ + h * 64;
            kbn[nt][0] = *(const bf16x8*)(kp + quad * 8);
            kbn[nt][1] = *(const bf16x8*)(kp + 32 + quad * 8);
        }

        int mk = 0;
        #pragma unroll
        for (int nt = 0; nt < 4; nt++)
            if (mb[k0 + nt*16 + l15] != 0) mk |= (1 << nt);

        #pragma unroll
        for (int mt = 0; mt < 2; mt++) {
            #pragma unroll
            for (int i = 0; i < 4; i++) {
                int qq = q0 + mt*16 + quad*4 + i;
                #pragma unroll
                for (int nt = 0; nt < 4; nt++) {
                    int kc = k0 + nt*16 + l15;
                    float p = exp2f(fmaf(s[mt][nt][i], SCL, -MMAX));
                    p = (kc <= qq && ((mk >> nt) & 1)) ? p : 0.f;
                    Pw[(mt*16 + quad*4 + i) * LDP + nt*16 + l15] = f2bf(p);
                }
            }
        }
        // same-wave P write -> read ordering (P is wave-private; LDS only —
        // the kbn global loads above stay in flight, they are vmcnt).
        asm volatile("s_waitcnt lgkmcnt(0)" ::: "memory");

        #pragma unroll
        for (int hv = 0; hv < 2; hv++) {
            bf16x8 ap0 = *(const bf16x8*)&Pw[l15 * LDP + hv*32 + quad*8];
            bf16x8 ap1 = *(const bf16x8*)&Pw[(16 + l15) * LDP + hv*32 + quad*8];
            #pragma unroll
            for (int d = 0; d < 4; d++) {
                o[0][d] = __builtin_amdgcn_mfma_f32_16x16x32_bf16(ap0, vb[d][hv], o[0][d], 0,0,0);
                o[1][d] = __builtin_amdgcn_mfma_f32_16x16x32_bf16(ap1, vb[d][hv], o[1][d], 0,0,0);
            }
            lacc[0] = __builtin_amdgcn_mfma_f32_16x16x32_bf16(ap0, ones, lacc[0], 0,0,0);
            lacc[1] = __builtin_amdgcn_mfma_f32_16x16x32_bf16(ap1, ones, lacc[1], 0,0,0);
        }

        // rotate prefetched K into place
        #pragma unroll
        for (int nt = 0; nt < 4; nt++) {
            kb[nt][0] = kbn[nt][0];
            kb[nt][1] = kbn[nt][1];
        }
    }

    #pragma unroll
    for (int mt = 0; mt < 2; mt++) {
        #pragma unroll
        for (int i = 0; i < 4; i++) {
            float inv = 1.f / lacc[mt][i];
            long r = tokBase + q0 + mt*16 + quad*4 + i;
            #pragma unroll
            for (int d = 0; d < 4; d++)
                O[r * D_ + h*64 + d*16 + l15] = f2bf(o[mt][d][i] * inv);
        }
    }
}

// ------------------------------------------------- launch
extern "C" void kernel_launch(void* const* d_in, const int* in_sizes, int n_in,
                              void* d_out, int out_size, void* d_ws, size_t ws_size,
                              hipStream_t stream) {
    const float* x    = (const float*)d_in[0];
    const int*   am   = (const int*)d_in[1];
    const float* ln1a = (const float*)d_in[2];
    const float* ln1b = (const float*)d_in[3];
    const float* ln2a = (const float*)d_in[4];
    const float* ln2b = (const float*)d_in[5];
    const float* wq   = (const float*)d_in[6];
    const float* wk   = (const float*)d_in[7];
    const float* wv   = (const float*)d_in[8];
    const float* wo   = (const float*)d_in[9];
    const float* w1   = (const float*)d_in[10];
    const float* b1   = (const float*)d_in[11];
    const float* w2   = (const float*)d_in[12];
    const float* b2   = (const float*)d_in[13];
    float* out = (float*)d_out;

    // Workspace: 72 MB, liveness-overlapped 16MB slots.
    char* ws = (char*)d_ws;
    const size_t MB16 = (size_t)16 * 1024 * 1024;
    u16* y1      = (u16*)(ws + 0 * MB16);
    u16* q       = (u16*)(ws + 1 * MB16);
    u16* k       = (u16*)(ws + 2 * MB16);
    u16* v       = (u16*)(ws + 3 * MB16);
    u16* wqt     = (u16*)(ws + 4 * MB16 + 0 * (size_t)D_ * D_ * 2);
    u16* wkt     = (u16*)(ws + 4 * MB16 + 1 * (size_t)D_ * D_ * 2);
    u16* wvt     = (u16*)(ws + 4 * MB16 + 2 * (size_t)D_ * D_ * 2);
    u16* wot     = (u16*)(ws + 4 * MB16 + 3 * (size_t)D_ * D_ * 2);
    u16* y2      = y1;
    u16* w1t     = q;
    u16* w2t     = q + (size_t)D_ * DFF;
    u16* h_full  = k;
    u16* ctx     = v;
    u16*   vt  = (u16*)d_out;                // d_out scratch; dead after attn
    float* x1f = out;

    dim3 tb(32, 8);
    transpose_f2b4<<<dim3(D_/32, D_/32, 4), tb, 0, stream>>>(
        wq, wk, wv, wo, wqt, wkt, wvt, wot, D_, D_);

    ln_kernel<<<NT, 256, 0, stream>>>(x, ln1a, ln1b, y1);

    // fused QKV: wqt/wkt/wvt are contiguous -> one [3072][1024] B matrix
    gemm8p<<<dim3(3*D_/BN2, NT/BM2), 512, 0, stream>>>(
        y1, wqt, q, k, v, 3*D_, D_, 0, nullptr);

    transpose_v<<<dim3(S_/32, 2, B_*H_), tb, 0, stream>>>(v, vt);

    attn_kernel<<<dim3(B_*H_, 16), 256, 0, stream>>>(q, k, vt, am, ctx);

    gemm_bt<<<dim3(D_/BN, NT/BM, 1), 256, 0, stream>>>(
        ctx, wot, wot, wot, x1f, x1f, x1f, NT, D_, D_, 1, nullptr, x);

    transpose_f2b<<<dim3(DFF/32, D_/32), tb, 0, stream>>>(w1, w1t, D_, DFF);
    transpose_f2b<<<dim3(D_/32, DFF/32), tb, 0, stream>>>(w2, w2t, DFF, D_);

    ln_kernel<<<NT, 256, 0, stream>>>(x1f, ln2a, ln2b, y2);

    gemm8p<<<dim3(DFF/BN2, NT/BM2), 512, 0, stream>>>(
        y2, w1t, h_full, h_full, h_full, DFF, D_, 2, b1);
    gemm_bt<<<dim3(D_/BN, NT/BM, 1), 256, 0, stream>>>(
        h_full, w2t, w2t, w2t, out, out, out, NT, D_, DFF, 3, b2, x1f);
}